// Round 10
// baseline (64.923 us; speedup 1.0000x reference)
//
#include <hip/hip_runtime.h>

// DETR-style NMS post-processor, v8.
// v7 post-mortem: kernel-internal improvement moved total 0 -> ~22us of the
// 42us is dispatch-boundary overhead (3 boundaries x ~7us). v8 keeps v4/v7's
// parallelism shape but removes 2 boundaries:
//   K1 (16 blocks x 1024): argmax inline (keys straight to registers) +
//       register bitonic sort + histogram compaction  [A+B fused]
//   K2 (1280 blocks x 64): per-(image,class) pair masks + greedy; the LAST
//       block per image (device-scope arrival counter) runs the finalize
//       selection+write with its 64 threads  [C+D fused]
// Decision math byte-identical to the absmax=0.0-validated path: f64 sigmoid
// threshold, f64 corners, divide-free f64 IoU>0.7, key=(~asc(score))<<32|idx.

#define NTHREADS 1024
constexpr int Bn = 16;    // batch
constexpr int Nn = 2048;  // queries
constexpr int Cc = 80;    // classes
constexpr int Kk = 300;   // keep topk
constexpr int CCAP = 64;  // per-class capacity (mean 25.6, ~7.6 sigma margin)
constexpr double IOU_THR = 0.7;
constexpr double SCORE_THR = 0.01;

__device__ unsigned long long g_skeys[Bn * Nn];   // K1 -> K2
__device__ unsigned char g_lab[Bn * Nn];          // K1 -> K2 (label per orig idx)
__device__ unsigned short g_clp[Bn * Cc * CCAP];  // K1 -> K2: sorted pos per (b,c,rank)
__device__ unsigned short g_cloi[Bn * Cc * CCAP]; // K1 -> K2: orig idx  per (b,c,rank)
__device__ int g_ccnt[Bn * Cc];                   // K1 -> K2
__device__ unsigned int g_keepw[Bn * (Nn / 32)];  // zeroed by K1; atomicOr'd in K2
__device__ unsigned int g_done[Bn];               // zeroed by K1; arrival counter in K2

// compare-exchange helper: keep min if takeMin else max (keys are unique)
__device__ __forceinline__ void cx(unsigned long long& a, unsigned long long p, bool takeMin)
{
    bool aless = a < p;
    a = (takeMin == aless) ? a : p;
}

// ---- Kernel 1: argmax + register bitonic sort + histogram compaction ----
__launch_bounds__(NTHREADS, 1)
__global__ void prep_kernel(const float* __restrict__ logits)
{
    __shared__ unsigned long long dbuf[2][Nn];   // 32 KB ping-pong for 14 LDS rounds
    __shared__ unsigned int hist[32 * Cc];       // 10 KB [chunk][class] -> excl. base
    __shared__ int s_nv;
    const int t = threadIdx.x;
    const int b = blockIdx.x;
    const size_t base = (size_t)b * Nn;

    if (t == 0) { s_nv = 0; g_done[b] = 0u; }
    if (t < Nn / 32) g_keepw[b * (Nn / 32) + t] = 0u;   // fresh keep state each call
    for (int i = t; i < 32 * Cc; i += NTHREADS) hist[i] = 0u;

    // inline argmax for this thread's two boxes (t and t+1024); build sort keys
    unsigned long long v0, v1;
    int vc = 0;
#pragma unroll
    for (int e = 0; e < 2; ++e) {
        const int n = t + (e << 10);
        const float4* lp = (const float4*)(logits + (base + n) * Cc);
        float m = -__builtin_inff();
        int am = 0;
#pragma unroll
        for (int c = 0; c < Cc / 4; ++c) {
            float4 v = lp[c];
            if (v.x > m) { m = v.x; am = 4 * c + 0; }   // strict > keeps FIRST max
            if (v.y > m) { m = v.y; am = 4 * c + 1; }
            if (v.z > m) { m = v.z; am = 4 * c + 2; }
            if (v.w > m) { m = v.w; am = 4 * c + 3; }
        }
        unsigned mb = __float_as_uint(m);
        unsigned asc = mb ^ ((mb & 0x80000000u) ? 0xFFFFFFFFu : 0x80000000u);
        unsigned long long key = ((unsigned long long)(~asc) << 32) | (unsigned)n;
        if (e) v1 = key; else v0 = key;
        g_lab[base + n] = (unsigned char)am;
        double sd = 1.0 / (1.0 + exp(-(double)m));      // f64 threshold decision
        if (sd > SCORE_THR) vc++;
    }
    for (int off = 32; off > 0; off >>= 1) vc += __shfl_down(vc, off);
    if ((t & 63) == 0) atomicAdd(&s_nv, vc);

    // register bitonic sort, ascending (=> score desc, idx asc) [v5/v7-validated]
    int cur = 0;
    for (int k = 2; k <= Nn; k <<= 1) {
        for (int j = k >> 1; j > 0; j >>= 1) {
            if (j >= 1024) {
                unsigned long long mn = (v0 < v1) ? v0 : v1;
                unsigned long long mx = (v0 < v1) ? v1 : v0;
                v0 = mn; v1 = mx;
            } else if (j >= 64) {
                dbuf[cur][t] = v0;
                dbuf[cur][t + 1024] = v1;
                __syncthreads();
                unsigned long long p0 = dbuf[cur][t ^ j];
                unsigned long long p1 = dbuf[cur][(t ^ j) + 1024];
                bool lower = ((t & j) == 0);
                cx(v0, p0, lower == ((t & k) == 0));
                cx(v1, p1, lower == (((t + 1024) & k) == 0));
                cur ^= 1;
            } else {
                unsigned long long p0 = __shfl_xor(v0, j);
                unsigned long long p1 = __shfl_xor(v1, j);
                bool lower = ((t & j) == 0);
                cx(v0, p0, lower == ((t & k) == 0));
                cx(v1, p1, lower == (((t + 1024) & k) == 0));
            }
        }
    }
    const int nv = s_nv;   // final: atomicAdds precede the sort's barriers

    // per-sorted-position labels (127 = below thr) + per-chunk histogram
    // (g_lab stores drained at the sort's first barrier; same-CU L1 reload)
    const int oi0 = (int)(v0 & 0xFFFFu);
    const int oi1 = (int)(v1 & 0xFFFFu);
    const int c0 = (t < nv) ? (int)g_lab[base + oi0] : 127;
    const int c1 = (t + 1024 < nv) ? (int)g_lab[base + oi1] : 127;
    if (c0 < 127) atomicAdd(&hist[(t >> 6) * Cc + c0], 1u);
    if (c1 < 127) atomicAdd(&hist[((t + 1024) >> 6) * Cc + c1], 1u);
    g_skeys[base + t] = v0;
    g_skeys[base + t + 1024] = v1;
    __syncthreads();

    // exclusive prefix per class across the 32 chunks [v4-validated]
    if (t < Cc) {
        unsigned run = 0;
        for (int ch = 0; ch < 32; ++ch) {
            unsigned v = hist[ch * Cc + t];
            hist[ch * Cc + t] = run;
            run += v;
        }
        g_ccnt[b * Cc + t] = (int)((run < CCAP) ? run : CCAP);
    }
    __syncthreads();

    // stable rank via 7-ballot match-any within each 64-chunk [v4-validated]
    const int l = t & 63;
    const unsigned long long below = (l == 0) ? 0ull : ((1ull << l) - 1ull);
#pragma unroll
    for (int e = 0; e < 2; ++e) {
        const int p = e ? (t + 1024) : t;
        const int c7 = e ? c1 : c0;
        const int oi = e ? oi1 : oi0;
        unsigned long long mm = ~0ull;
#pragma unroll
        for (int bit = 0; bit < 7; ++bit) {
            unsigned long long vote = __ballot((c7 >> bit) & 1);
            mm &= ((c7 >> bit) & 1) ? vote : ~vote;
        }
        if (c7 < 127) {
            int r = (int)hist[(p >> 6) * Cc + c7] + __popcll(mm & below);
            if (r < CCAP) {
                g_clp[((size_t)b * Cc + c7) * CCAP + r] = (unsigned short)p;
                g_cloi[((size_t)b * Cc + c7) * CCAP + r] = (unsigned short)oi;
            }
        }
    }
}

// ---- Kernel 2: per-(image,class) pair NMS; last block per image finalizes ----
__launch_bounds__(64, 8)
__global__ void nms_finalize_kernel(const float* __restrict__ pboxes,
                                    const float* __restrict__ osize,
                                    float* __restrict__ out)
{
    __shared__ double lb[CCAP][5];     // x1,y1,x2,y2,area (f64)
    __shared__ unsigned int kw[Nn / 32];
    __shared__ int kpre[Nn / 32];
    __shared__ int out_posS[Kk];
    __shared__ int s_kept;
    __shared__ int s_last;

    const int bc = blockIdx.x;         // b*Cc + c
    const int b = bc / Cc;
    const int t = threadIdx.x;         // 64 threads; lane = within-class rank
    const int cnt = g_ccnt[bc];
    const double s0 = (double)osize[2 * b + 0];
    const double s1 = (double)osize[2 * b + 1];

    if (cnt > 0) {                     // block-uniform branch [v4/v7-validated body]
        const int j = t;
        unsigned short p = 0;
        double jx1 = 0, jy1 = 0, jx2 = 0, jy2 = 0, aj = 0;
        if (j < cnt) {
            p = g_clp[(size_t)bc * CCAP + j];
            int oi = g_cloi[(size_t)bc * CCAP + j];
            const float* bp = pboxes + ((size_t)b * Nn + oi) * 4;
            double cx = (double)bp[0], cy = (double)bp[1];
            double w  = (double)bp[2], h  = (double)bp[3];
            jx1 = (cx - 0.5 * w) * s0; jy1 = (cy - 0.5 * h) * s1;
            jx2 = (cx + 0.5 * w) * s0; jy2 = (cy + 0.5 * h) * s1;
            aj = (jx2 - jx1) * (jy2 - jy1);
            lb[j][0] = jx1; lb[j][1] = jy1; lb[j][2] = jx2; lb[j][3] = jy2; lb[j][4] = aj;
        }
        __syncthreads();

        unsigned long long mymask = 0ull;
        if (j < cnt) {
            for (int i = 0; i < j; ++i) {   // uniform lb[i] reads = LDS broadcast
                double lt0 = fmax(lb[i][0], jx1), lt1 = fmax(lb[i][1], jy1);
                double rb0 = fmin(lb[i][2], jx2), rb1 = fmin(lb[i][3], jy2);
                double w0 = fmax(rb0 - lt0, 0.0), w1 = fmax(rb1 - lt1, 0.0);
                double inter = w0 * w1;
                double uni = lb[i][4] + aj - inter;
                if (uni > 0.0 && inter > IOU_THR * uni) mymask |= 1ull << i;
            }
        }
        unsigned long long K = 0ull;
        for (int r = 0; r < cnt; ++r) {
            unsigned long long mr = __shfl(mymask, r);
            if ((mr & K) == 0ull) K |= 1ull << r;
        }
        if (j < cnt && ((K >> j) & 1ull))
            atomicOr(&g_keepw[b * (Nn / 32) + (p >> 5)], 1u << (p & 31));
    }

    // arrival: all 80 blocks of image b (incl. cnt==0) count in; last finalizes
    __syncthreads();                      // drain this block's atomicOrs (vmcnt(0))
    if (t == 0) {
        __threadfence();                  // release keep-bits device-wide
        unsigned old = atomicAdd(&g_done[b], 1u);
        s_last = (old == (unsigned)(Cc - 1)) ? 1 : 0;
    }
    __syncthreads();
    if (!s_last) return;

    // ---- finalize (v7-D logic, 64 threads, fresh atomic reads of keep bits) ----
    {
        unsigned w = atomicAdd(&g_keepw[b * (Nn / 32) + t], 0u);  // device-coherent read
        kw[t] = w;
        int pc = __popc(w);
        int inc = pc;
        for (int off = 1; off < 64; off <<= 1) {
            int v = __shfl_up(inc, off);
            if (t >= off) inc += v;
        }
        kpre[t] = inc - pc;
        if (t == 63) s_kept = (inc < Kk) ? inc : Kk;
    }
    __syncthreads();
    for (int p = t; p < Nn; p += 64) {
        if ((kw[p >> 5] >> (p & 31)) & 1u) {
            int rank = kpre[p >> 5] + __popc(kw[p >> 5] & ((1u << (p & 31)) - 1u));
            if (rank < Kk) out_posS[rank] = p;
        }
    }
    __syncthreads();

    const int kept = s_kept;
    const int base_b = Bn * Kk;
    const int base_s = Bn * Kk * 5;
    for (int r = t; r < Kk; r += 64) {
        float lf = -1.0f, b0 = 0.f, b1 = 0.f, b2 = 0.f, b3 = 0.f, sf = 0.f;
        if (r < kept) {
            int p = out_posS[r];
            unsigned long long kk = g_skeys[(size_t)b * Nn + p];
            unsigned oi = (unsigned)(kk & 0xFFFFu);
            lf = (float)g_lab[(size_t)b * Nn + oi];
            unsigned hi = (unsigned)(kk >> 32);
            unsigned ascb = ~hi;
            unsigned mb = (ascb & 0x80000000u) ? (ascb ^ 0x80000000u) : ~ascb;
            float m = __uint_as_float(mb);
            sf = (float)(1.0 / (1.0 + exp(-(double)m)));
            const float* bp = pboxes + ((size_t)b * Nn + oi) * 4;
            double cx = (double)bp[0], cy = (double)bp[1];
            double w  = (double)bp[2], h  = (double)bp[3];
            b0 = (float)((cx - 0.5 * w) * s0);
            b1 = (float)((cy - 0.5 * h) * s1);
            b2 = (float)((cx + 0.5 * w) * s0);
            b3 = (float)((cy + 0.5 * h) * s1);
        }
        out[b * Kk + r] = lf;
        float* ob = out + base_b + (size_t)(b * Kk + r) * 4;
        ob[0] = b0; ob[1] = b1; ob[2] = b2; ob[3] = b3;
        out[base_s + b * Kk + r] = sf;
    }
}

extern "C" void kernel_launch(void* const* d_in, const int* in_sizes, int n_in,
                              void* d_out, int out_size, void* d_ws, size_t ws_size,
                              hipStream_t stream)
{
    const float* logits = (const float*)d_in[0];
    const float* pboxes = (const float*)d_in[1];
    const float* osize  = (const float*)d_in[2];
    float* out = (float*)d_out;
    prep_kernel<<<Bn, NTHREADS, 0, stream>>>(logits);
    nms_finalize_kernel<<<Bn * Cc, 64, 0, stream>>>(pboxes, osize, out);
}